// Round 1
// baseline (1717.157 us; speedup 1.0000x reference)
//
#include <hip/hip_runtime.h>
#include <math.h>

typedef _Float16 f16;
typedef _Float16 f16x8 __attribute__((ext_vector_type(8)));
typedef float f32x4 __attribute__((ext_vector_type(4)));

#define NTOK 98
#define NPAD 112   // 7*16
#define BWIN 2048

// ---------------- workspace layout (bytes) ----------------
#define OFF_BT    0u                      // 507*8*4
#define OFF_RPB   (1u<<20)                // 8*98*98*4 = 307328
#define OFF_WQKV  (2u<<20)                // 768*256*2
#define OFF_WPROJ (3u<<20)                // 256*256*2
#define OFF_Q     (4u<<20)
#define QKV_SZ    (2048u*8u*98u*32u*2u)   // 102,760,448
#define OFF_K     (OFF_Q + QKV_SZ)
#define OFF_V     (OFF_K + QKV_SZ)
#define OFF_AV    (OFF_V + QKV_SZ)        // av: 2048*98*256*2

// orderable-uint encoding of float for atomicMax
__device__ __forceinline__ unsigned fenc(float f) {
  unsigned u = __float_as_uint(f);
  return (u & 0x80000000u) ? ~u : (u | 0x80000000u);
}
__device__ __forceinline__ float fdec(unsigned k) {
  unsigned u = (k & 0x80000000u) ? (k & 0x7fffffffu) : ~k;
  return __uint_as_float(u);
}

// ---------------- prep: cpb MLP -> bt[507][8] ----------------
__global__ void prep_bt(const float* __restrict__ w1, const float* __restrict__ b1,
                        const float* __restrict__ w2, float* __restrict__ bt) {
  int t = blockIdx.x;            // 0..506
  int lane = threadIdx.x;        // 64
  int a = t / 169, rem = t % 169, b = rem / 13, c = rem % 13;
  // matches numpy fp32: g/(W-(1-1e-6)) * 8; sign*log2(|g|+1)/3
  float g0 = ((float)(a - 1) / 1.000001f) * 8.0f;
  float g1 = ((float)(b - 6) / 6.000001f) * 8.0f;
  float g2 = ((float)(c - 6) / 6.000001f) * 8.0f;
  float t0 = log2f(fabsf(g0) + 1.0f) / 3.0f; t0 = (g0 < 0.f) ? -t0 : t0;
  float t1 = log2f(fabsf(g1) + 1.0f) / 3.0f; t1 = (g1 < 0.f) ? -t1 : t1;
  float t2 = log2f(fabsf(g2) + 1.0f) / 3.0f; t2 = (g2 < 0.f) ? -t2 : t2;
  float part[8] = {0.f,0.f,0.f,0.f,0.f,0.f,0.f,0.f};
#pragma unroll
  for (int jj = 0; jj < 8; jj++) {
    int j = lane * 8 + jj;
    float hv = t0 * w1[j*3] + t1 * w1[j*3+1] + t2 * w1[j*3+2] + b1[j];
    hv = fmaxf(hv, 0.f);
#pragma unroll
    for (int h = 0; h < 8; h++) part[h] += hv * w2[h*512 + j];
  }
#pragma unroll
  for (int m = 1; m < 64; m <<= 1)
#pragma unroll
    for (int h = 0; h < 8; h++) part[h] += __shfl_xor(part[h], m);
  if (lane == 0)
#pragma unroll
    for (int h = 0; h < 8; h++) bt[t*8 + h] = part[h];
}

// ---------------- prep: gather + sigmoid -> rpb[8][98][98] fp32 ----------------
__global__ void prep_rpb(const float* __restrict__ bt, float* __restrict__ rpb) {
  int bid = blockIdx.x;          // 8*98
  int h = bid / 98, i = bid % 98;
  int j = threadIdx.x;
  if (j >= 98) return;
  int di = i / 49, hi = (i % 49) / 7, wi = i % 7;
  int dj = j / 49, hj = (j % 49) / 7, wj = j % 7;
  int idx = (di - dj + 1) * 169 + (hi - hj + 6) * 13 + (wi - wj + 6);
  float v = bt[idx*8 + h];
  rpb[(h*98 + i)*98 + j] = 16.0f / (1.0f + expf(-v));
}

// ---------------- prep: weight fp32 -> fp16 ----------------
__global__ void prep_wt(const float* __restrict__ qkv_w, const float* __restrict__ proj_w,
                        f16* __restrict__ wq, f16* __restrict__ wp) {
  int t = blockIdx.x * 256 + threadIdx.x;   // grid covers 768*256
  wq[t] = (f16)qkv_w[t];
  if (t < 256*256) wp[t] = (f16)proj_w[t];
}

// ---------------- QKV GEMM: [200704,256] x [256,768] ----------------
#define ASTR 40
#define BSTR 264
__global__ __launch_bounds__(256) void qkv_gemm(
    const float* __restrict__ x, const f16* __restrict__ wq,
    const float* __restrict__ q_bias, const float* __restrict__ v_bias,
    f16* __restrict__ qw, f16* __restrict__ kw, f16* __restrict__ vw) {
  __shared__ f16 Al[128*ASTR];
  __shared__ f16 Bl[64*BSTR];
  int tid = threadIdx.x;
  int w = tid >> 6, lane = tid & 63, q4 = lane >> 4, l15 = lane & 15;
  int m0 = blockIdx.x * 128;
  int n0 = blockIdx.y * 64;

  // stage B once: 64 rows (output cols) x 256 k, fp16
#pragma unroll
  for (int p = 0; p < 8; p++) {
    int e = tid + p*256;  int r = e >> 5, kc = e & 31;
    *(uint4*)(&Bl[r*BSTR + kc*8]) = *(const uint4*)(wq + (size_t)(n0 + r)*256 + kc*8);
  }
  f32x4 acc[2][4] = {};
  for (int ks = 0; ks < 8; ks++) {
    __syncthreads();
    // stage A: 128 x 32, fp32 -> fp16
#pragma unroll
    for (int p = 0; p < 4; p++) {
      int e = tid + p*256;  int r = e >> 3, kc = e & 7;
      float4 v = *(const float4*)(x + (size_t)(m0 + r)*256 + ks*32 + kc*4);
      union { f16 h[4]; uint2 u; } cv;
      cv.h[0] = (f16)v.x; cv.h[1] = (f16)v.y; cv.h[2] = (f16)v.z; cv.h[3] = (f16)v.w;
      *(uint2*)(&Al[r*ASTR + kc*4]) = cv.u;
    }
    __syncthreads();
    f16x8 af[2], bf[4];
#pragma unroll
    for (int mt = 0; mt < 2; mt++)
      af[mt] = *(const f16x8*)(&Al[(w*32 + mt*16 + l15)*ASTR + q4*8]);
#pragma unroll
    for (int nt = 0; nt < 4; nt++)
      bf[nt] = *(const f16x8*)(&Bl[(nt*16 + l15)*BSTR + ks*32 + q4*8]);
#pragma unroll
    for (int mt = 0; mt < 2; mt++)
#pragma unroll
      for (int nt = 0; nt < 4; nt++)
        acc[mt][nt] = __builtin_amdgcn_mfma_f32_16x16x32_f16(af[mt], bf[nt], acc[mt][nt], 0, 0, 0);
  }
  // epilogue: +bias, scatter to q/k/v [b][h][tok][d] fp16
#pragma unroll
  for (int mt = 0; mt < 2; mt++)
#pragma unroll
    for (int nt = 0; nt < 4; nt++) {
      int c = n0 + nt*16 + l15;
      int s = c >> 8, hcol = (c >> 5) & 7, d = c & 31;
      float bias = (s == 0) ? q_bias[c & 255] : ((s == 2) ? v_bias[c & 255] : 0.0f);
      f16* dst = (s == 0) ? qw : ((s == 1) ? kw : vw);
#pragma unroll
      for (int r = 0; r < 4; r++) {
        int m = m0 + w*32 + mt*16 + q4*4 + r;
        int b = m / 98, tok = m % 98;
        dst[((size_t)(b*8 + hcol)*98 + tok)*32 + d] = (f16)(acc[mt][nt][r] + bias);
      }
    }
}

// ---------------- attention per (window, head) ----------------
#define P_STR 136
#define VT_STR 136
__global__ __launch_bounds__(256) void attn_kernel(
    const f16* __restrict__ qw, const f16* __restrict__ kw, const f16* __restrict__ vw,
    const float* __restrict__ rpb, const float* __restrict__ logit_scale,
    f16* __restrict__ av) {
  __shared__ f16 Qs[NPAD*ASTR];     // normalized q, [112][40]
  __shared__ f16 Ks[NPAD*ASTR];     // normalized k
  __shared__ f16 Vt[32*VT_STR];     // V transposed [d][k], k padded to 128
  __shared__ f16 Ps[NPAD*P_STR];    // P = exp(logit - rowmax), [112][136]
  __shared__ float rsum[NPAD];
  __shared__ unsigned rmax_u[NPAD];
  __shared__ float rmaxf[NPAD];

  int tid = threadIdx.x;
  int wv = tid >> 6, lane = tid & 63, q4 = lane >> 4, l15 = lane & 15;
  int b = blockIdx.x >> 3, h = blockIdx.x & 7;
  float scale = expf(fminf(logit_scale[h], 4.6051701859880914f));
  const f16* qg = qw + ((size_t)(b*8 + h)*98)*32;
  const f16* kg = kw + ((size_t)(b*8 + h)*98)*32;
  const f16* vg = vw + ((size_t)(b*8 + h)*98)*32;

  // ---- phase 1: load + normalize q,k; transpose v; zero pads ----
  if (tid < NPAD) {
    int r = tid;
    rsum[r] = 0.f;
    rmax_u[r] = 0u;
    if (r < 98) {
      f16 buf[32];
#pragma unroll
      for (int c = 0; c < 4; c++) *(uint4*)(&buf[c*8]) = *(const uint4*)(qg + r*32 + c*8);
      float ss = 0.f;
#pragma unroll
      for (int i = 0; i < 32; i++) { float fv = (float)buf[i]; ss += fv*fv; }
      float inv = 1.0f / fmaxf(sqrtf(ss), 1e-12f);
#pragma unroll
      for (int i = 0; i < 32; i++) buf[i] = (f16)((float)buf[i] * inv);
#pragma unroll
      for (int c = 0; c < 4; c++) *(uint4*)(&Qs[r*ASTR + c*8]) = *(uint4*)(&buf[c*8]);
#pragma unroll
      for (int c = 0; c < 4; c++) *(uint4*)(&buf[c*8]) = *(const uint4*)(kg + r*32 + c*8);
      ss = 0.f;
#pragma unroll
      for (int i = 0; i < 32; i++) { float fv = (float)buf[i]; ss += fv*fv; }
      inv = 1.0f / fmaxf(sqrtf(ss), 1e-12f);
#pragma unroll
      for (int i = 0; i < 32; i++) buf[i] = (f16)((float)buf[i] * inv);
#pragma unroll
      for (int c = 0; c < 4; c++) *(uint4*)(&Ks[r*ASTR + c*8]) = *(uint4*)(&buf[c*8]);
    } else {
      uint4 z = {0,0,0,0};
#pragma unroll
      for (int c = 0; c < 4; c++) { *(uint4*)(&Qs[r*ASTR + c*8]) = z; *(uint4*)(&Ks[r*ASTR + c*8]) = z; }
    }
  }
  // v transpose (k < 98)
  if (tid < 196) {
    int r = tid >> 1, d0 = (tid & 1) * 16;
    f16 vbuf[16];
    *(uint4*)(&vbuf[0]) = *(const uint4*)(vg + r*32 + d0);
    *(uint4*)(&vbuf[8]) = *(const uint4*)(vg + r*32 + d0 + 8);
#pragma unroll
    for (int d = 0; d < 16; d++) Vt[(d0 + d)*VT_STR + r] = vbuf[d];
  }
  // zero Vt k in [98,128)
  for (int e = tid; e < 32*30; e += 256) { int d = e / 30, kk = 98 + e % 30; Vt[d*VT_STR + kk] = (f16)0.f; }
  // zero Ps cols [112,128)
  {
    uint4 z = {0,0,0,0};
    for (int e = tid; e < NPAD*2; e += 256) { int r = e >> 1, c0 = 112 + (e & 1)*8; *(uint4*)(&Ps[r*P_STR + c0]) = z; }
  }
  __syncthreads();

  // ---- phase 2a: S tiles -> logits in regs, rowmax via shfl + atomicMax ----
  float lg[13][4];
#pragma unroll
  for (int i = 0; i < 13; i++) {
    int t = wv + 4*i;
    if (t < 49) {
      int mt = t / 7, nt = t % 7;
      f16x8 a = *(const f16x8*)(&Qs[(mt*16 + l15)*ASTR + q4*8]);
      f16x8 bf = *(const f16x8*)(&Ks[(nt*16 + l15)*ASTR + q4*8]);
      f32x4 z = {0.f,0.f,0.f,0.f};
      f32x4 acc = __builtin_amdgcn_mfma_f32_16x16x32_f16(a, bf, z, 0, 0, 0);
      int col = nt*16 + l15;
#pragma unroll
      for (int r = 0; r < 4; r++) {
        int row = mt*16 + q4*4 + r;
        float lv = -1e30f;
        if (row < 98 && col < 98)
          lv = scale * acc[r] + rpb[(h*98 + row)*98 + col];
        lg[i][r] = lv;
        float mx = lv;
        mx = fmaxf(mx, __shfl_xor(mx, 1));
        mx = fmaxf(mx, __shfl_xor(mx, 2));
        mx = fmaxf(mx, __shfl_xor(mx, 4));
        mx = fmaxf(mx, __shfl_xor(mx, 8));
        if (l15 == 0) atomicMax(&rmax_u[row], fenc(mx));
      }
    }
  }
  __syncthreads();
  if (tid < NPAD) rmaxf[tid] = fdec(rmax_u[tid]);
  __syncthreads();

  // ---- phase 2b: P = exp(logit - rowmax) fp16, rowsum via shfl + atomicAdd ----
#pragma unroll
  for (int i = 0; i < 13; i++) {
    int t = wv + 4*i;
    if (t < 49) {
      int mt = t / 7, nt = t % 7;
      int col = nt*16 + l15;
#pragma unroll
      for (int r = 0; r < 4; r++) {
        int row = mt*16 + q4*4 + r;
        float p = expf(lg[i][r] - rmaxf[row]);
        Ps[row*P_STR + col] = (f16)p;
        float sm = p;
        sm += __shfl_xor(sm, 1);
        sm += __shfl_xor(sm, 2);
        sm += __shfl_xor(sm, 4);
        sm += __shfl_xor(sm, 8);
        if (l15 == 0) atomicAdd(&rsum[row], sm);
      }
    }
  }
  __syncthreads();
  if (tid < NPAD) rsum[tid] = 1.0f / rsum[tid];
  __syncthreads();

  // ---- phase 3: AV = P @ V, rescale, store ----
#pragma unroll
  for (int i = 0; i < 4; i++) {
    int t = wv + 4*i;
    if (t < 14) {
      int mt = t >> 1, nt = t & 1;
      f32x4 acc = {0.f,0.f,0.f,0.f};
#pragma unroll
      for (int ks = 0; ks < 4; ks++) {
        f16x8 a = *(const f16x8*)(&Ps[(mt*16 + l15)*P_STR + ks*32 + q4*8]);
        f16x8 bf = *(const f16x8*)(&Vt[(nt*16 + l15)*VT_STR + ks*32 + q4*8]);
        acc = __builtin_amdgcn_mfma_f32_16x16x32_f16(a, bf, acc, 0, 0, 0);
      }
      int d = nt*16 + l15;
#pragma unroll
      for (int r = 0; r < 4; r++) {
        int row = mt*16 + q4*4 + r;
        if (row < 98)
          av[((size_t)(b*98 + row))*256 + h*32 + d] = (f16)(acc[r] * rsum[row]);
      }
    }
  }
}

// ---------------- proj GEMM: [200704,256] x [256,256] + bias -> fp32 out ----------------
__global__ __launch_bounds__(256) void proj_gemm(
    const f16* __restrict__ avi, const f16* __restrict__ wp,
    const float* __restrict__ pb, float* __restrict__ out) {
  __shared__ f16 Al[128*ASTR];
  __shared__ f16 Bl[64*BSTR];
  int tid = threadIdx.x;
  int w = tid >> 6, lane = tid & 63, q4 = lane >> 4, l15 = lane & 15;
  int m0 = blockIdx.x * 128;
  int n0 = blockIdx.y * 64;
#pragma unroll
  for (int p = 0; p < 8; p++) {
    int e = tid + p*256;  int r = e >> 5, kc = e & 31;
    *(uint4*)(&Bl[r*BSTR + kc*8]) = *(const uint4*)(wp + (size_t)(n0 + r)*256 + kc*8);
  }
  f32x4 acc[2][4] = {};
  for (int ks = 0; ks < 8; ks++) {
    __syncthreads();
#pragma unroll
    for (int p = 0; p < 2; p++) {
      int e = tid + p*256;  int r = e >> 2, kc = e & 3;
      *(uint4*)(&Al[r*ASTR + kc*8]) = *(const uint4*)(avi + (size_t)(m0 + r)*256 + ks*32 + kc*8);
    }
    __syncthreads();
    f16x8 af[2], bf[4];
#pragma unroll
    for (int mt = 0; mt < 2; mt++)
      af[mt] = *(const f16x8*)(&Al[(w*32 + mt*16 + l15)*ASTR + q4*8]);
#pragma unroll
    for (int nt = 0; nt < 4; nt++)
      bf[nt] = *(const f16x8*)(&Bl[(nt*16 + l15)*BSTR + ks*32 + q4*8]);
#pragma unroll
    for (int mt = 0; mt < 2; mt++)
#pragma unroll
      for (int nt = 0; nt < 4; nt++)
        acc[mt][nt] = __builtin_amdgcn_mfma_f32_16x16x32_f16(af[mt], bf[nt], acc[mt][nt], 0, 0, 0);
  }
#pragma unroll
  for (int mt = 0; mt < 2; mt++)
#pragma unroll
    for (int nt = 0; nt < 4; nt++) {
      int c = n0 + nt*16 + l15;
      float bias = pb[c];
#pragma unroll
      for (int r = 0; r < 4; r++) {
        int m = m0 + w*32 + mt*16 + q4*4 + r;
        out[(size_t)m*256 + c] = acc[mt][nt][r] + bias;
      }
    }
}

extern "C" void kernel_launch(void* const* d_in, const int* in_sizes, int n_in,
                              void* d_out, int out_size, void* d_ws, size_t ws_size,
                              hipStream_t stream) {
  const float* x           = (const float*)d_in[0];
  const float* qkv_w       = (const float*)d_in[1];
  const float* q_bias      = (const float*)d_in[2];
  const float* v_bias      = (const float*)d_in[3];
  const float* logit_scale = (const float*)d_in[4];
  const float* cpb_w1      = (const float*)d_in[5];
  const float* cpb_b1      = (const float*)d_in[6];
  const float* cpb_w2      = (const float*)d_in[7];
  const float* proj_w      = (const float*)d_in[8];
  const float* proj_b      = (const float*)d_in[9];
  char* ws = (char*)d_ws;
  float* bt  = (float*)(ws + OFF_BT);
  float* rpb = (float*)(ws + OFF_RPB);
  f16* wq    = (f16*)(ws + OFF_WQKV);
  f16* wp    = (f16*)(ws + OFF_WPROJ);
  f16* qws   = (f16*)(ws + OFF_Q);
  f16* kws   = (f16*)(ws + OFF_K);
  f16* vws   = (f16*)(ws + OFF_V);
  f16* avs   = (f16*)(ws + OFF_AV);
  float* out = (float*)d_out;

  prep_bt<<<dim3(507), dim3(64), 0, stream>>>(cpb_w1, cpb_b1, cpb_w2, bt);
  prep_rpb<<<dim3(784), dim3(128), 0, stream>>>(bt, rpb);
  prep_wt<<<dim3(768), dim3(256), 0, stream>>>(qkv_w, proj_w, wq, wp);
  qkv_gemm<<<dim3(1568, 12), dim3(256), 0, stream>>>(x, wq, q_bias, v_bias, qws, kws, vws);
  attn_kernel<<<dim3(16384), dim3(256), 0, stream>>>(qws, kws, vws, rpb, logit_scale, avs);
  proj_gemm<<<dim3(1568, 4), dim3(256), 0, stream>>>(avs, wp, proj_b, out);
}

// Round 2
// 861.747 us; speedup vs baseline: 1.9926x; 1.9926x over previous
//
#include <hip/hip_runtime.h>
#include <math.h>

typedef _Float16 f16;
typedef _Float16 f16x8 __attribute__((ext_vector_type(8)));
typedef float f32x4 __attribute__((ext_vector_type(4)));

#define NTOK 98
#define BWIN 2048

// ---------------- workspace layout (bytes) ----------------
#define OFF_BT    0u                      // 507*8*4
#define OFF_RPB   (1u<<20)                // 8*98*98*4
#define OFF_WQKV  (2u<<20)                // 768*256*2
#define OFF_WPROJ (3u<<20)                // 256*256*2
#define OFF_Q     (4u<<20)
#define QKV_SZ    (2048u*8u*98u*32u*2u)   // 102,760,448
#define OFF_K     (OFF_Q + QKV_SZ)
#define OFF_V     (OFF_K + QKV_SZ)
#define OFF_AV    (OFF_V + QKV_SZ)        // av: 2048*98*256*2 == QKV_SZ
#define OFF_X16   OFF_AV                  // x16 (51380224 f16) aliases av: disjoint lifetimes

// ---------------- prep: cpb MLP -> bt[507][8] ----------------
__global__ void prep_bt(const float* __restrict__ w1, const float* __restrict__ b1,
                        const float* __restrict__ w2, float* __restrict__ bt) {
  int t = blockIdx.x;            // 0..506
  int lane = threadIdx.x;        // 64
  int a = t / 169, rem = t % 169, b = rem / 13, c = rem % 13;
  float g0 = ((float)(a - 1) / 1.000001f) * 8.0f;
  float g1 = ((float)(b - 6) / 6.000001f) * 8.0f;
  float g2 = ((float)(c - 6) / 6.000001f) * 8.0f;
  float t0 = log2f(fabsf(g0) + 1.0f) / 3.0f; t0 = (g0 < 0.f) ? -t0 : t0;
  float t1 = log2f(fabsf(g1) + 1.0f) / 3.0f; t1 = (g1 < 0.f) ? -t1 : t1;
  float t2 = log2f(fabsf(g2) + 1.0f) / 3.0f; t2 = (g2 < 0.f) ? -t2 : t2;
  float part[8] = {0.f,0.f,0.f,0.f,0.f,0.f,0.f,0.f};
#pragma unroll
  for (int jj = 0; jj < 8; jj++) {
    int j = lane * 8 + jj;
    float hv = t0 * w1[j*3] + t1 * w1[j*3+1] + t2 * w1[j*3+2] + b1[j];
    hv = fmaxf(hv, 0.f);
#pragma unroll
    for (int h = 0; h < 8; h++) part[h] += hv * w2[h*512 + j];
  }
#pragma unroll
  for (int m = 1; m < 64; m <<= 1)
#pragma unroll
    for (int h = 0; h < 8; h++) part[h] += __shfl_xor(part[h], m);
  if (lane == 0)
#pragma unroll
    for (int h = 0; h < 8; h++) bt[t*8 + h] = part[h];
}

// ---------------- prep: gather + sigmoid -> rpb[8][98][98] fp32 ----------------
__global__ void prep_rpb(const float* __restrict__ bt, float* __restrict__ rpb) {
  int bid = blockIdx.x;          // 8*98
  int h = bid / 98, i = bid % 98;
  int j = threadIdx.x;
  if (j >= 98) return;
  int di = i / 49, hi = (i % 49) / 7, wi = i % 7;
  int dj = j / 49, hj = (j % 49) / 7, wj = j % 7;
  int idx = (di - dj + 1) * 169 + (hi - hj + 6) * 13 + (wi - wj + 6);
  float v = bt[idx*8 + h];
  rpb[(h*98 + i)*98 + j] = 16.0f / (1.0f + expf(-v));
}

// ---------------- prep: weights fp32 -> fp16 ----------------
__global__ void prep_wt(const float* __restrict__ qkv_w, const float* __restrict__ proj_w,
                        f16* __restrict__ wq, f16* __restrict__ wp) {
  int t = blockIdx.x * 256 + threadIdx.x;   // grid covers 768*256
  wq[t] = (f16)qkv_w[t];
  if (t < 256*256) wp[t] = (f16)proj_w[t];
}

// ---------------- prep: x fp32 -> fp16 ----------------
__global__ __launch_bounds__(256) void prep_x16(const float* __restrict__ x, f16* __restrict__ x16) {
  size_t i = ((size_t)blockIdx.x * 256 + threadIdx.x) * 8;
  float4 a = *(const float4*)(x + i);
  float4 b = *(const float4*)(x + i + 4);
  f16x8 o;
  o[0]=(f16)a.x; o[1]=(f16)a.y; o[2]=(f16)a.z; o[3]=(f16)a.w;
  o[4]=(f16)b.x; o[5]=(f16)b.y; o[6]=(f16)b.z; o[7]=(f16)b.w;
  *(f16x8*)(x16 + i) = o;
}

// ---------------- QKV GEMM: [200704,256](f16) x [256,768] -> q/k/v scatter ----------------
#define ASTR 40
__global__ __launch_bounds__(256) void qkv_gemm(
    const f16* __restrict__ x16, const f16* __restrict__ wq,
    const float* __restrict__ q_bias, const float* __restrict__ v_bias,
    f16* __restrict__ qw, f16* __restrict__ kw, f16* __restrict__ vw) {
  __shared__ f16 Al[128*ASTR];
  __shared__ f16 Bl[128*ASTR];
  int tid = threadIdx.x;
  int w = tid >> 6, lane = tid & 63, q4 = lane >> 4, l15 = lane & 15;
  int m0 = blockIdx.x * 128;
  int n0 = blockIdx.y * 128;

  f32x4 acc[2][8] = {};
  for (int ks = 0; ks < 8; ks++) {
    __syncthreads();
#pragma unroll
    for (int p = 0; p < 2; p++) {
      int e = tid + p*256;  int r = e >> 2, kc = e & 3;
      *(uint4*)(&Al[r*ASTR + kc*8]) = *(const uint4*)(x16 + (size_t)(m0 + r)*256 + ks*32 + kc*8);
      *(uint4*)(&Bl[r*ASTR + kc*8]) = *(const uint4*)(wq  + (size_t)(n0 + r)*256 + ks*32 + kc*8);
    }
    __syncthreads();
    f16x8 af[2], bf[8];
#pragma unroll
    for (int mt = 0; mt < 2; mt++)
      af[mt] = *(const f16x8*)(&Al[(w*32 + mt*16 + l15)*ASTR + q4*8]);
#pragma unroll
    for (int nt = 0; nt < 8; nt++)
      bf[nt] = *(const f16x8*)(&Bl[(nt*16 + l15)*ASTR + q4*8]);
#pragma unroll
    for (int mt = 0; mt < 2; mt++)
#pragma unroll
      for (int nt = 0; nt < 8; nt++)
        acc[mt][nt] = __builtin_amdgcn_mfma_f32_16x16x32_f16(af[mt], bf[nt], acc[mt][nt], 0, 0, 0);
  }
  // epilogue: +bias, scatter to q/k/v [b][h][tok][d] fp16. s uniform per block.
  int s = blockIdx.y >> 1;
  f16* dst = (s == 0) ? qw : ((s == 1) ? kw : vw);
#pragma unroll
  for (int mt = 0; mt < 2; mt++)
#pragma unroll
    for (int nt = 0; nt < 8; nt++) {
      int c = n0 + nt*16 + l15;
      int hcol = (c >> 5) & 7, d = c & 31;
      float bias = (s == 0) ? q_bias[c & 255] : ((s == 2) ? v_bias[c & 255] : 0.0f);
#pragma unroll
      for (int r = 0; r < 4; r++) {
        int m = m0 + w*32 + mt*16 + q4*4 + r;
        int b = m / 98, tok = m % 98;
        dst[((size_t)(b*8 + hcol)*98 + tok)*32 + d] = (f16)(acc[mt][nt][r] + bias);
      }
    }
}

// ---------------- attention: ONE WAVE per (window, head), no barriers/atomics ----------------
#define P_STR 136
__global__ __launch_bounds__(256) void attn_kernel(
    const f16* __restrict__ qw, const f16* __restrict__ kw, const f16* __restrict__ vw,
    const float* __restrict__ rpb, const float* __restrict__ logit_scale,
    f16* __restrict__ av) {
  __shared__ f16 Ps[4*16*P_STR];   // per-wave 16x136 P bounce (C-layout -> A-layout)

  int tid = threadIdx.x;
  int wv = tid >> 6, lane = tid & 63, q4 = lane >> 4, l15 = lane & 15;
  int pair = blockIdx.x * 4 + wv;
  int b = pair >> 3, h = pair & 7;
  float scale = __expf(fminf(logit_scale[h], 4.6051701859880914f));
  const f16* qg = qw + ((size_t)pair) * (98*32);
  const f16* kg = kw + ((size_t)pair) * (98*32);
  const f16* vg = vw + ((size_t)pair) * (98*32);
  f16* pbuf = &Ps[wv * 16 * P_STR];

  // zero P cols [112,128) once (never rewritten)
  {
    int r = lane >> 2, c0 = 112 + (lane & 3) * 4;
    *(ushort4*)(&pbuf[r*P_STR + c0]) = ushort4{0,0,0,0};
  }

  // ---- K fragments, L2-normalized, resident in regs ----
  f16x8 kf[7];
#pragma unroll
  for (int nt = 0; nt < 7; nt++) {
    int row = nt*16 + l15; if (row > 97) row = 97;
    f16x8 raw = *(const f16x8*)(kg + row*32 + q4*8);
    float ss = 0.f;
#pragma unroll
    for (int j = 0; j < 8; j++) { float v = (float)raw[j]; ss = fmaf(v, v, ss); }
    ss += __shfl_xor(ss, 16);
    ss += __shfl_xor(ss, 32);
    float inv = 1.0f / fmaxf(sqrtf(ss), 1e-12f);
#pragma unroll
    for (int j = 0; j < 8; j++) kf[nt][j] = (f16)((float)raw[j] * inv);
  }

  // ---- V fragments: B-layout (needs V^T) via scalar loads, resident ----
  f16x8 vf[2][4];
#pragma unroll
  for (int n = 0; n < 2; n++)
#pragma unroll
    for (int kt = 0; kt < 4; kt++)
#pragma unroll
      for (int j = 0; j < 8; j++) {
        int tok = kt*32 + q4*8 + j; if (tok > 97) tok = 97;
        vf[n][kt][j] = vg[tok*32 + n*16 + l15];
      }

  const float* rpb_h = rpb + (size_t)h * 98 * 98;

  // ---- 7 row strips of 16 ----
  for (int mt = 0; mt < 7; mt++) {
    // Q strip fragment, normalized
    int qrow = mt*16 + l15; if (qrow > 97) qrow = 97;
    f16x8 qraw = *(const f16x8*)(qg + qrow*32 + q4*8);
    float ss = 0.f;
#pragma unroll
    for (int j = 0; j < 8; j++) { float v = (float)qraw[j]; ss = fmaf(v, v, ss); }
    ss += __shfl_xor(ss, 16);
    ss += __shfl_xor(ss, 32);
    float qinv = 1.0f / fmaxf(sqrtf(ss), 1e-12f);
    f16x8 aq;
#pragma unroll
    for (int j = 0; j < 8; j++) aq[j] = (f16)((float)qraw[j] * qinv);

    // S tiles -> logits
    f32x4 lg[7];
#pragma unroll
    for (int nt = 0; nt < 7; nt++) {
      f32x4 z = {0.f,0.f,0.f,0.f};
      lg[nt] = __builtin_amdgcn_mfma_f32_16x16x32_f16(aq, kf[nt], z, 0, 0, 0);
    }
#pragma unroll
    for (int nt = 0; nt < 7; nt++) {
      int col = nt*16 + l15;
#pragma unroll
      for (int r = 0; r < 4; r++) {
        int row = mt*16 + q4*4 + r;
        float lv = -1e30f;
        if (row < 98 && col < 98)
          lv = fmaf(scale, lg[nt][r], rpb_h[row*98 + col]);
        lg[nt][r] = lv;
      }
    }
    // row max (7 fmax + 4 shfls per r)
    float mx[4];
#pragma unroll
    for (int r = 0; r < 4; r++) {
      float m = lg[0][r];
#pragma unroll
      for (int nt = 1; nt < 7; nt++) m = fmaxf(m, lg[nt][r]);
      m = fmaxf(m, __shfl_xor(m, 1));
      m = fmaxf(m, __shfl_xor(m, 2));
      m = fmaxf(m, __shfl_xor(m, 4));
      m = fmaxf(m, __shfl_xor(m, 8));
      mx[r] = m;
    }
    // exp, row sum, write P strip (cols 98..111 become exp(-inf)=0)
    float rs[4] = {0.f,0.f,0.f,0.f};
#pragma unroll
    for (int nt = 0; nt < 7; nt++) {
      int col = nt*16 + l15;
#pragma unroll
      for (int r = 0; r < 4; r++) {
        float p = __expf(lg[nt][r] - mx[r]);
        rs[r] += p;
        pbuf[(q4*4 + r)*P_STR + col] = (f16)p;
      }
    }
    float inv[4];
#pragma unroll
    for (int r = 0; r < 4; r++) {
      float s = rs[r];
      s += __shfl_xor(s, 1);
      s += __shfl_xor(s, 2);
      s += __shfl_xor(s, 4);
      s += __shfl_xor(s, 8);
      inv[r] = 1.0f / s;
    }
    // P C-layout -> A-layout via wave-private LDS (in-order DS, no barrier)
    f16x8 pf[4];
#pragma unroll
    for (int kt = 0; kt < 4; kt++)
      pf[kt] = *(const f16x8*)(&pbuf[l15*P_STR + kt*32 + q4*8]);
    // AV
#pragma unroll
    for (int n = 0; n < 2; n++) {
      f32x4 acc = {0.f,0.f,0.f,0.f};
#pragma unroll
      for (int kt = 0; kt < 4; kt++)
        acc = __builtin_amdgcn_mfma_f32_16x16x32_f16(pf[kt], vf[n][kt], acc, 0, 0, 0);
      int d = n*16 + l15;
#pragma unroll
      for (int r = 0; r < 4; r++) {
        int row = mt*16 + q4*4 + r;
        if (row < 98)
          av[((size_t)(b*98 + row))*256 + h*32 + d] = (f16)(acc[r] * inv[r]);
      }
    }
  }
}

// ---------------- proj GEMM: [200704,256](f16) x [256,256] + bias -> fp32 out ----------------
__global__ __launch_bounds__(256) void proj_gemm(
    const f16* __restrict__ avi, const f16* __restrict__ wp,
    const float* __restrict__ pb, float* __restrict__ out) {
  __shared__ f16 Al[128*ASTR];
  __shared__ f16 Bl[128*ASTR];
  int tid = threadIdx.x;
  int w = tid >> 6, lane = tid & 63, q4 = lane >> 4, l15 = lane & 15;
  int m0 = blockIdx.x * 128;
  int n0 = blockIdx.y * 128;

  f32x4 acc[2][8] = {};
  for (int ks = 0; ks < 8; ks++) {
    __syncthreads();
#pragma unroll
    for (int p = 0; p < 2; p++) {
      int e = tid + p*256;  int r = e >> 2, kc = e & 3;
      *(uint4*)(&Al[r*ASTR + kc*8]) = *(const uint4*)(avi + (size_t)(m0 + r)*256 + ks*32 + kc*8);
      *(uint4*)(&Bl[r*ASTR + kc*8]) = *(const uint4*)(wp  + (size_t)(n0 + r)*256 + ks*32 + kc*8);
    }
    __syncthreads();
    f16x8 af[2], bf[8];
#pragma unroll
    for (int mt = 0; mt < 2; mt++)
      af[mt] = *(const f16x8*)(&Al[(w*32 + mt*16 + l15)*ASTR + q4*8]);
#pragma unroll
    for (int nt = 0; nt < 8; nt++)
      bf[nt] = *(const f16x8*)(&Bl[(nt*16 + l15)*ASTR + q4*8]);
#pragma unroll
    for (int mt = 0; mt < 2; mt++)
#pragma unroll
      for (int nt = 0; nt < 8; nt++)
        acc[mt][nt] = __builtin_amdgcn_mfma_f32_16x16x32_f16(af[mt], bf[nt], acc[mt][nt], 0, 0, 0);
  }
#pragma unroll
  for (int mt = 0; mt < 2; mt++)
#pragma unroll
    for (int nt = 0; nt < 8; nt++) {
      int c = n0 + nt*16 + l15;
      float bias = pb[c];
#pragma unroll
      for (int r = 0; r < 4; r++) {
        int m = m0 + w*32 + mt*16 + q4*4 + r;
        out[(size_t)m*256 + c] = acc[mt][nt][r] + bias;
      }
    }
}

extern "C" void kernel_launch(void* const* d_in, const int* in_sizes, int n_in,
                              void* d_out, int out_size, void* d_ws, size_t ws_size,
                              hipStream_t stream) {
  const float* x           = (const float*)d_in[0];
  const float* qkv_w       = (const float*)d_in[1];
  const float* q_bias      = (const float*)d_in[2];
  const float* v_bias      = (const float*)d_in[3];
  const float* logit_scale = (const float*)d_in[4];
  const float* cpb_w1      = (const float*)d_in[5];
  const float* cpb_b1      = (const float*)d_in[6];
  const float* cpb_w2      = (const float*)d_in[7];
  const float* proj_w      = (const float*)d_in[8];
  const float* proj_b      = (const float*)d_in[9];
  char* ws = (char*)d_ws;
  float* bt  = (float*)(ws + OFF_BT);
  float* rpb = (float*)(ws + OFF_RPB);
  f16* wq    = (f16*)(ws + OFF_WQKV);
  f16* wp    = (f16*)(ws + OFF_WPROJ);
  f16* qws   = (f16*)(ws + OFF_Q);
  f16* kws   = (f16*)(ws + OFF_K);
  f16* vws   = (f16*)(ws + OFF_V);
  f16* avs   = (f16*)(ws + OFF_AV);
  f16* x16   = (f16*)(ws + OFF_X16);   // aliases avs; x16 dead before attn writes avs
  float* out = (float*)d_out;

  prep_bt<<<dim3(507), dim3(64), 0, stream>>>(cpb_w1, cpb_b1, cpb_w2, bt);
  prep_rpb<<<dim3(784), dim3(128), 0, stream>>>(bt, rpb);
  prep_wt<<<dim3(768), dim3(256), 0, stream>>>(qkv_w, proj_w, wq, wp);
  prep_x16<<<dim3(25088), dim3(256), 0, stream>>>(x, x16);
  qkv_gemm<<<dim3(1568, 6), dim3(256), 0, stream>>>(x16, wq, q_bias, v_bias, qws, kws, vws);
  attn_kernel<<<dim3(4096), dim3(256), 0, stream>>>(qws, kws, vws, rpb, logit_scale, avs);
  proj_gemm<<<dim3(1568, 2), dim3(256), 0, stream>>>(avs, wp, proj_b, out);
}